// Round 1
// baseline (1077.947 us; speedup 1.0000x reference)
//
#include <hip/hip_runtime.h>
#include <math.h>

#define NN 50000
#define NE 600000
#define NF 256
#define NHID 128
#define HEADS 8
#define D0 16
#define NCLS 64
#define LEAKY 0.2f

// ---------------- utility ----------------

__device__ __forceinline__ void atomicMaxF(float* addr, float val) {
    // standard signed-max / unsigned-min trick; init must be -inf
    if (val >= 0.f) {
        atomicMax((int*)addr, __float_as_int(val));
    } else {
        atomicMin((unsigned int*)addr, __float_as_uint(val));
    }
}

__global__ void fill_kernel(float* __restrict__ p, float v, int n) {
    int i = blockIdx.x * 256 + threadIdx.x;
    if (i < n) p[i] = v;
}

// ---------------- GEMM (fp32, tiled) ----------------
// C[M,N] = A[M,K] @ B[K,N]; N,K multiples of tile; M guarded.
template <int BM, int BN, int BK, int TM, int TN>
__global__ void gemm_f32(const float* __restrict__ A, const float* __restrict__ B,
                         float* __restrict__ C, int M, int N, int K) {
    __shared__ float As[BK][BM + 4];
    __shared__ float Bs[BK][BN];
    const int tid = threadIdx.x;
    const int nThreads = (BM / TM) * (BN / TN);  // 256
    const int bm = blockIdx.x * BM;
    const int bn = blockIdx.y * BN;
    const int tx = tid % (BN / TN);
    const int ty = tid / (BN / TN);
    float acc[TM][TN] = {};
    for (int k0 = 0; k0 < K; k0 += BK) {
        for (int l = tid; l < BM * BK; l += nThreads) {
            int m = l / BK, k = l % BK;
            int gm = bm + m;
            As[k][m] = (gm < M) ? A[(size_t)gm * K + k0 + k] : 0.f;
        }
        for (int l = tid; l < BK * BN; l += nThreads) {
            int n = l % BN, k = l / BN;
            Bs[k][n] = B[(size_t)(k0 + k) * N + bn + n];
        }
        __syncthreads();
#pragma unroll
        for (int k = 0; k < BK; ++k) {
            float a[TM], b[TN];
#pragma unroll
            for (int i = 0; i < TM; ++i) a[i] = As[k][ty * TM + i];
#pragma unroll
            for (int j = 0; j < TN; ++j) b[j] = Bs[k][tx * TN + j];
#pragma unroll
            for (int i = 0; i < TM; ++i)
#pragma unroll
                for (int j = 0; j < TN; ++j) acc[i][j] += a[i] * b[j];
        }
        __syncthreads();
    }
    for (int i = 0; i < TM; ++i) {
        int gm = bm + ty * TM + i;
        if (gm >= M) continue;
        for (int j = 0; j < TN; ++j)
            C[(size_t)gm * N + bn + tx * TN + j] = acc[i][j];
    }
}

// ---------------- per-node attention logits ----------------
// as_out[n*H+h] = dot(h[n,h,:], a_s[h,:]); same for ad_out.
__global__ void alpha_kernel(const float* __restrict__ h, const float* __restrict__ a_s,
                             const float* __restrict__ a_d, float* __restrict__ as_out,
                             float* __restrict__ ad_out, int D) {
    int idx = blockIdx.x * blockDim.x + threadIdx.x;
    if (idx >= NN * HEADS) return;
    int n = idx / HEADS, hh = idx % HEADS;
    const float* hp = h + (size_t)n * HEADS * D + hh * D;
    const float* asp = a_s + hh * D;
    const float* adp = a_d + hh * D;
    float s = 0.f, d = 0.f;
    for (int i = 0; i < D; ++i) {
        float v = hp[i];
        s += v * asp[i];
        d += v * adp[i];
    }
    as_out[idx] = s;
    ad_out[idx] = d;
}

// ---------------- edge passes ----------------
__global__ void edge_max_kernel(const int* __restrict__ ei, const float* __restrict__ as,
                                const float* __restrict__ ad, float* __restrict__ m) {
    int idx = blockIdx.x * blockDim.x + threadIdx.x;
    if (idx >= NE * HEADS) return;
    int e = idx / HEADS, hh = idx % HEADS;
    int s = ei[e], d = ei[NE + e];
    float v = as[s * HEADS + hh] + ad[d * HEADS + hh];
    v = v > 0.f ? v : LEAKY * v;
    atomicMaxF(&m[d * HEADS + hh], v);
}

__global__ void edge_exp_kernel(const int* __restrict__ ei, const float* __restrict__ as,
                                const float* __restrict__ ad, const float* __restrict__ m,
                                float* __restrict__ ex, float* __restrict__ denom) {
    int idx = blockIdx.x * blockDim.x + threadIdx.x;
    if (idx >= NE * HEADS) return;
    int e = idx / HEADS, hh = idx % HEADS;
    int s = ei[e], d = ei[NE + e];
    float v = as[s * HEADS + hh] + ad[d * HEADS + hh];
    v = v > 0.f ? v : LEAKY * v;
    float e_ = expf(v - m[d * HEADS + hh]);
    ex[idx] = e_;
    atomicAdd(&denom[d * HEADS + hh], e_);
}

// layer-0 aggregate: agg[d, j] += h[s, j] * alpha(e, j/16)
__global__ void edge_agg0_kernel(const int* __restrict__ ei, const float* __restrict__ h,
                                 const float* __restrict__ ex, const float* __restrict__ denom,
                                 float* __restrict__ agg) {
    int idx = blockIdx.x * blockDim.x + threadIdx.x;
    if (idx >= NE * NHID) return;  // 76.8M < 2^31
    int e = idx / NHID, j = idx % NHID;
    int hh = j / D0;
    int s = ei[e], d = ei[NE + e];
    float alpha = ex[e * HEADS + hh] / (denom[d * HEADS + hh] + 1e-16f);
    atomicAdd(&agg[(size_t)d * NHID + j], h[(size_t)s * NHID + j] * alpha);
}

// h_in = elu(agg + b0), in place
__global__ void elu_bias_kernel(float* __restrict__ agg, const float* __restrict__ b) {
    int idx = blockIdx.x * blockDim.x + threadIdx.x;
    if (idx >= NN * NHID) return;
    int j = idx % NHID;
    float v = agg[idx] + b[j];
    agg[idx] = v > 0.f ? v : expf(v) - 1.f;
}

// layer-1 aggregate with fused head-mean:
// pre[d, c] += (1/8) * sum_h h1[s, h, c] * alpha(e, h)
__global__ void edge_agg1_kernel(const int* __restrict__ ei, const float* __restrict__ h1,
                                 const float* __restrict__ ex, const float* __restrict__ denom,
                                 float* __restrict__ pre) {
    int idx = blockIdx.x * blockDim.x + threadIdx.x;
    if (idx >= NE * NCLS) return;  // 38.4M
    int e = idx / NCLS, c = idx % NCLS;
    int s = ei[e], d = ei[NE + e];
    float sum = 0.f;
#pragma unroll
    for (int hh = 0; hh < HEADS; ++hh) {
        float alpha = ex[e * HEADS + hh] / (denom[d * HEADS + hh] + 1e-16f);
        sum += h1[(size_t)s * (HEADS * NCLS) + hh * NCLS + c] * alpha;
    }
    atomicAdd(&pre[(size_t)d * NCLS + c], 0.125f * sum);
}

// out[n, c] = z - max - log(sum(exp(z - max))), z = pre[n,c] + b1[c]
__global__ void logsoftmax_kernel(const float* __restrict__ pre, const float* __restrict__ b,
                                  float* __restrict__ out) {
    int gid = blockIdx.x * blockDim.x + threadIdx.x;
    int n = gid / 64;
    int c = threadIdx.x % 64;
    if (n >= NN) return;
    float z = pre[(size_t)n * 64 + c] + b[c];
    float mx = z;
#pragma unroll
    for (int off = 32; off > 0; off >>= 1) mx = fmaxf(mx, __shfl_xor(mx, off, 64));
    float s = expf(z - mx);
#pragma unroll
    for (int off = 32; off > 0; off >>= 1) s += __shfl_xor(s, off, 64);
    out[(size_t)n * 64 + c] = z - mx - logf(s);
}

// ---------------- launch ----------------

extern "C" void kernel_launch(void* const* d_in, const int* in_sizes, int n_in,
                              void* d_out, int out_size, void* d_ws, size_t ws_size,
                              hipStream_t stream) {
    const float* x   = (const float*)d_in[0];
    const int*   ei  = (const int*)d_in[1];
    const float* W0  = (const float*)d_in[2];
    const float* aS0 = (const float*)d_in[3];
    const float* aD0 = (const float*)d_in[4];
    const float* b0  = (const float*)d_in[5];
    const float* W1  = (const float*)d_in[6];
    const float* aS1 = (const float*)d_in[7];
    const float* aD1 = (const float*)d_in[8];
    const float* b1  = (const float*)d_in[9];
    float* out = (float*)d_out;

    char* ws = (char*)d_ws;
    float* h0    = (float*)ws; ws += (size_t)NN * NHID * 4;          // 25.6 MB
    float* agg0  = (float*)ws; ws += (size_t)NN * NHID * 4;          // 25.6 MB (becomes h_in)
    float* h1    = (float*)ws; ws += (size_t)NN * HEADS * NCLS * 4;  // 102.4 MB
    float* as0   = (float*)ws; ws += (size_t)NN * HEADS * 4;
    float* ad0   = (float*)ws; ws += (size_t)NN * HEADS * 4;
    float* m0    = (float*)ws; ws += (size_t)NN * HEADS * 4;
    float* dn0   = (float*)ws; ws += (size_t)NN * HEADS * 4;
    float* as1   = (float*)ws; ws += (size_t)NN * HEADS * 4;
    float* ad1   = (float*)ws; ws += (size_t)NN * HEADS * 4;
    float* m1    = (float*)ws; ws += (size_t)NN * HEADS * 4;
    float* dn1   = (float*)ws; ws += (size_t)NN * HEADS * 4;
    float* ex0   = (float*)ws; ws += (size_t)NE * HEADS * 4;         // 19.2 MB
    float* ex1   = (float*)ws; ws += (size_t)NE * HEADS * 4;         // 19.2 MB
    float* pre1  = (float*)ws; ws += (size_t)NN * NCLS * 4;          // 12.8 MB

    const int NH = NN * HEADS;          // 400000
    const int EH = NE * HEADS;          // 4.8M

    // zero accumulators (ws is poisoned before every call)
    hipMemsetAsync(dn0, 0, (size_t)NH * 4, stream);
    hipMemsetAsync(dn1, 0, (size_t)NH * 4, stream);
    hipMemsetAsync(agg0, 0, (size_t)NN * NHID * 4, stream);
    hipMemsetAsync(pre1, 0, (size_t)NN * NCLS * 4, stream);
    fill_kernel<<<(NH + 255) / 256, 256, 0, stream>>>(m0, -INFINITY, NH);
    fill_kernel<<<(NH + 255) / 256, 256, 0, stream>>>(m1, -INFINITY, NH);

    // ---- layer 0 ----
    gemm_f32<64, 64, 16, 4, 4><<<dim3((NN + 63) / 64, NHID / 64), 256, 0, stream>>>(
        x, W0, h0, NN, NHID, NF);
    alpha_kernel<<<(NH + 255) / 256, 256, 0, stream>>>(h0, aS0, aD0, as0, ad0, D0);
    edge_max_kernel<<<(EH + 255) / 256, 256, 0, stream>>>(ei, as0, ad0, m0);
    edge_exp_kernel<<<(EH + 255) / 256, 256, 0, stream>>>(ei, as0, ad0, m0, ex0, dn0);
    edge_agg0_kernel<<<(NE * NHID + 255) / 256, 256, 0, stream>>>(ei, h0, ex0, dn0, agg0);
    elu_bias_kernel<<<(NN * NHID + 255) / 256, 256, 0, stream>>>(agg0, b0);

    // ---- layer 1 ----
    gemm_f32<64, 64, 16, 4, 4><<<dim3((NN + 63) / 64, (HEADS * NCLS) / 64), 256, 0, stream>>>(
        agg0, W1, h1, NN, HEADS * NCLS, NHID);
    alpha_kernel<<<(NH + 255) / 256, 256, 0, stream>>>(h1, aS1, aD1, as1, ad1, NCLS);
    edge_max_kernel<<<(EH + 255) / 256, 256, 0, stream>>>(ei, as1, ad1, m1);
    edge_exp_kernel<<<(EH + 255) / 256, 256, 0, stream>>>(ei, as1, ad1, m1, ex1, dn1);
    edge_agg1_kernel<<<(NE * NCLS + 255) / 256, 256, 0, stream>>>(ei, h1, ex1, dn1, pre1);

    // ---- output ----
    logsoftmax_kernel<<<(NN * 64 + 255) / 256, 256, 0, stream>>>(pre1, b1, out);
}

// Round 2
// 654.765 us; speedup vs baseline: 1.6463x; 1.6463x over previous
//
#include <hip/hip_runtime.h>
#include <hip/hip_bf16.h>
#include <math.h>

#define NN 50000
#define NE 600000
#define NF 256
#define NHID 128
#define HEADS 8
#define D0 16
#define NCLS 64
#define NB1 196  // (NN+255)/256

// ---------------- CSR build ----------------

__global__ void deg_kernel(const int* __restrict__ ei, int* __restrict__ deg) {
    int e = blockIdx.x * 256 + threadIdx.x;
    if (e < NE) atomicAdd(&deg[ei[NE + e]], 1);
}

__global__ void scan1_kernel(const int* __restrict__ deg, int* __restrict__ rs,
                             int* __restrict__ bsum) {
    __shared__ int sh[256];
    int tid = threadIdx.x;
    int i = blockIdx.x * 256 + tid;
    int v = (i < NN) ? deg[i] : 0;
    sh[tid] = v;
    __syncthreads();
    for (int off = 1; off < 256; off <<= 1) {
        int t = (tid >= off) ? sh[tid - off] : 0;
        __syncthreads();
        sh[tid] += t;
        __syncthreads();
    }
    if (i < NN) rs[i] = sh[tid] - v;  // exclusive
    if (tid == 255) bsum[blockIdx.x] = sh[255];
}

__global__ void scan2_kernel(const int* __restrict__ bsum, int* __restrict__ bsumx) {
    __shared__ int sh[256];
    int tid = threadIdx.x;
    int v = (tid < NB1) ? bsum[tid] : 0;
    sh[tid] = v;
    __syncthreads();
    for (int off = 1; off < 256; off <<= 1) {
        int t = (tid >= off) ? sh[tid - off] : 0;
        __syncthreads();
        sh[tid] += t;
        __syncthreads();
    }
    if (tid < NB1) bsumx[tid] = sh[tid] - v;
}

__global__ void scan3_kernel(int* __restrict__ rs, const int* __restrict__ bsumx) {
    int i = blockIdx.x * 256 + threadIdx.x;
    if (i < NN) rs[i] += bsumx[i >> 8];
}

__global__ void scatter_kernel(const int* __restrict__ ei, const int* __restrict__ rs,
                               int* __restrict__ cnt2, int* __restrict__ csr) {
    int e = blockIdx.x * 256 + threadIdx.x;
    if (e >= NE) return;
    int s = ei[e], d = ei[NE + e];
    int pos = rs[d] + atomicAdd(&cnt2[d], 1);
    csr[pos] = s;
}

// ---------------- GEMM (fp32, tiled) ----------------
template <int BM, int BN, int BK, int TM, int TN>
__global__ void gemm_f32(const float* __restrict__ A, const float* __restrict__ B,
                         float* __restrict__ C, int M, int N, int K) {
    __shared__ float As[BK][BM + 4];
    __shared__ float Bs[BK][BN];
    const int tid = threadIdx.x;
    const int nThreads = (BM / TM) * (BN / TN);
    const int bm = blockIdx.x * BM;
    const int bn = blockIdx.y * BN;
    const int tx = tid % (BN / TN);
    const int ty = tid / (BN / TN);
    float acc[TM][TN] = {};
    for (int k0 = 0; k0 < K; k0 += BK) {
        for (int l = tid; l < BM * BK; l += nThreads) {
            int m = l / BK, k = l % BK;
            int gm = bm + m;
            As[k][m] = (gm < M) ? A[(size_t)gm * K + k0 + k] : 0.f;
        }
        for (int l = tid; l < BK * BN; l += nThreads) {
            int n = l % BN, k = l / BN;
            Bs[k][n] = B[(size_t)(k0 + k) * N + bn + n];
        }
        __syncthreads();
#pragma unroll
        for (int k = 0; k < BK; ++k) {
            float a[TM], b[TN];
#pragma unroll
            for (int i = 0; i < TM; ++i) a[i] = As[k][ty * TM + i];
#pragma unroll
            for (int j = 0; j < TN; ++j) b[j] = Bs[k][tx * TN + j];
#pragma unroll
            for (int i = 0; i < TM; ++i)
#pragma unroll
                for (int j = 0; j < TN; ++j) acc[i][j] += a[i] * b[j];
        }
        __syncthreads();
    }
    for (int i = 0; i < TM; ++i) {
        int gm = bm + ty * TM + i;
        if (gm >= M) continue;
        for (int j = 0; j < TN; ++j)
            C[(size_t)gm * N + bn + tx * TN + j] = acc[i][j];
    }
}

// same but A is bf16
template <int BM, int BN, int BK, int TM, int TN>
__global__ void gemm_bf16A(const __hip_bfloat16* __restrict__ A, const float* __restrict__ B,
                           float* __restrict__ C, int M, int N, int K) {
    __shared__ float As[BK][BM + 4];
    __shared__ float Bs[BK][BN];
    const int tid = threadIdx.x;
    const int nThreads = (BM / TM) * (BN / TN);
    const int bm = blockIdx.x * BM;
    const int bn = blockIdx.y * BN;
    const int tx = tid % (BN / TN);
    const int ty = tid / (BN / TN);
    float acc[TM][TN] = {};
    for (int k0 = 0; k0 < K; k0 += BK) {
        for (int l = tid; l < BM * BK; l += nThreads) {
            int m = l / BK, k = l % BK;
            int gm = bm + m;
            As[k][m] = (gm < M) ? __bfloat162float(A[(size_t)gm * K + k0 + k]) : 0.f;
        }
        for (int l = tid; l < BK * BN; l += nThreads) {
            int n = l % BN, k = l / BN;
            Bs[k][n] = B[(size_t)(k0 + k) * N + bn + n];
        }
        __syncthreads();
#pragma unroll
        for (int k = 0; k < BK; ++k) {
            float a[TM], b[TN];
#pragma unroll
            for (int i = 0; i < TM; ++i) a[i] = As[k][ty * TM + i];
#pragma unroll
            for (int j = 0; j < TN; ++j) b[j] = Bs[k][tx * TN + j];
#pragma unroll
            for (int i = 0; i < TM; ++i)
#pragma unroll
                for (int j = 0; j < TN; ++j) acc[i][j] += a[i] * b[j];
        }
        __syncthreads();
    }
    for (int i = 0; i < TM; ++i) {
        int gm = bm + ty * TM + i;
        if (gm >= M) continue;
        for (int j = 0; j < TN; ++j)
            C[(size_t)gm * N + bn + tx * TN + j] = acc[i][j];
    }
}

// ---------------- attention logits ----------------
__global__ void alpha_kernel(const float* __restrict__ h, const float* __restrict__ a_s,
                             const float* __restrict__ a_d, float* __restrict__ as_out,
                             float* __restrict__ ad_out, int D) {
    int idx = blockIdx.x * blockDim.x + threadIdx.x;
    if (idx >= NN * HEADS) return;
    int n = idx / HEADS, hh = idx % HEADS;
    const float* hp = h + (size_t)n * HEADS * D + hh * D;
    const float* asp = a_s + hh * D;
    const float* adp = a_d + hh * D;
    float s = 0.f, d = 0.f;
    for (int i = 0; i < D; ++i) {
        float v = hp[i];
        s += v * asp[i];
        d += v * adp[i];
    }
    as_out[idx] = s;
    ad_out[idx] = d;
}

// w~[h,k] = sum_d W1[k, h*64+d] * a[h,d]
__global__ void wtil_kernel(const float* __restrict__ W1, const float* __restrict__ aS,
                            const float* __restrict__ aD, float* __restrict__ wS,
                            float* __restrict__ wD) {
    int tid = blockIdx.x * 256 + threadIdx.x;
    if (tid >= HEADS * NHID) return;
    int h = tid / NHID, k = tid % NHID;
    float sS = 0.f, sD = 0.f;
    for (int d2 = 0; d2 < NCLS; ++d2) {
        float w = W1[(size_t)k * (HEADS * NCLS) + h * NCLS + d2];
        sS += w * aS[h * NCLS + d2];
        sD += w * aD[h * NCLS + d2];
    }
    wS[tid] = sS;
    wD[tid] = sD;
}

// as1[n,h] = x1[n,:] . wS[h,:]
__global__ void alpha1_kernel(const float* __restrict__ x1, const float* __restrict__ wS,
                              const float* __restrict__ wD, float* __restrict__ as_out,
                              float* __restrict__ ad_out) {
    int idx = blockIdx.x * 256 + threadIdx.x;
    if (idx >= NN * HEADS) return;
    int n = idx / HEADS, h = idx % HEADS;
    const float* xp = x1 + (size_t)n * NHID;
    const float* sp = wS + h * NHID;
    const float* dp = wD + h * NHID;
    float s = 0.f, d = 0.f;
    for (int k = 0; k < NHID; ++k) {
        float v = xp[k];
        s += v * sp[k];
        d += v * dp[k];
    }
    as_out[idx] = s;
    ad_out[idx] = d;
}

// ---------------- fused edge kernels (one wave per dst node) ----------------

// layer 0: out x1[d, 0..128) = elu( (sum_e p*h0[s,:]) / den + b0 )
__global__ __launch_bounds__(256) void fused_edge0(
    const int* __restrict__ rs, const int* __restrict__ deg, const int* __restrict__ csr,
    const float* __restrict__ h0, const float* __restrict__ as0, const float* __restrict__ ad0,
    const float* __restrict__ b0, float* __restrict__ x1) {
    int d = (blockIdx.x * 256 + threadIdx.x) >> 6;
    int lane = threadIdx.x & 63;
    if (d >= NN) return;
    int row = rs[d], dg = deg[d];
    int hl = lane & 7, g = lane >> 3;
    float adv = ad0[d * 8 + hl];
    float m = -INFINITY;
    for (int base = 0; base < dg; base += 8) {
        int i = base + g;
        int s = (i < dg) ? csr[row + i] : 0;
        float ev = as0[s * 8 + hl] + adv;
        ev = ev > 0.f ? ev : 0.2f * ev;
        if (i < dg) m = fmaxf(m, ev);
    }
    m = fmaxf(m, __shfl_xor(m, 8));
    m = fmaxf(m, __shfl_xor(m, 16));
    m = fmaxf(m, __shfl_xor(m, 32));
    float den = 0.f, acc0 = 0.f, acc1 = 0.f;
    int hd0 = lane >> 4;  // head of dim `lane` (0..3); dim lane+64 -> hd0+4
    for (int base = 0; base < dg; base += 8) {
        int i = base + g;
        int s = (i < dg) ? csr[row + i] : 0;
        float ev = as0[s * 8 + hl] + adv;
        ev = ev > 0.f ? ev : 0.2f * ev;
        float p = (i < dg) ? expf(ev - m) : 0.f;
        den += p;
        int nv = dg - base;
        if (nv > 8) nv = 8;
        for (int g2 = 0; g2 < nv; ++g2) {
            int sg = __shfl(s, g2 * 8);
            float p0 = __shfl(p, g2 * 8 + hd0);
            float p1 = __shfl(p, g2 * 8 + hd0 + 4);
            acc0 += h0[(size_t)sg * NHID + lane] * p0;
            acc1 += h0[(size_t)sg * NHID + 64 + lane] * p1;
        }
    }
    den += __shfl_xor(den, 8);
    den += __shfl_xor(den, 16);
    den += __shfl_xor(den, 32);
    float d0 = __shfl(den, hd0);
    float d1 = __shfl(den, hd0 + 4);
    float o0 = acc0 / (d0 + 1e-16f) + b0[lane];
    float o1 = acc1 / (d1 + 1e-16f) + b0[64 + lane];
    o0 = o0 > 0.f ? o0 : expf(o0) - 1.f;
    o1 = o1 > 0.f ? o1 : expf(o1) - 1.f;
    x1[(size_t)d * NHID + lane] = o0;
    x1[(size_t)d * NHID + 64 + lane] = o1;
}

// layer 1: AGG[d, h*128+k] = (sum_e p_eh * x1[s,k]) / den_h   (bf16 out)
__global__ __launch_bounds__(256) void fused_edge1(
    const int* __restrict__ rs, const int* __restrict__ deg, const int* __restrict__ csr,
    const float* __restrict__ x1, const float* __restrict__ as1, const float* __restrict__ ad1,
    __hip_bfloat16* __restrict__ AGG) {
    int d = (blockIdx.x * 256 + threadIdx.x) >> 6;
    int lane = threadIdx.x & 63;
    if (d >= NN) return;
    int row = rs[d], dg = deg[d];
    int hl = lane & 7, g = lane >> 3;
    float adv = ad1[d * 8 + hl];
    float m = -INFINITY;
    for (int base = 0; base < dg; base += 8) {
        int i = base + g;
        int s = (i < dg) ? csr[row + i] : 0;
        float ev = as1[s * 8 + hl] + adv;
        ev = ev > 0.f ? ev : 0.2f * ev;
        if (i < dg) m = fmaxf(m, ev);
    }
    m = fmaxf(m, __shfl_xor(m, 8));
    m = fmaxf(m, __shfl_xor(m, 16));
    m = fmaxf(m, __shfl_xor(m, 32));
    float den = 0.f;
    float acc[HEADS][2] = {};
    for (int base = 0; base < dg; base += 8) {
        int i = base + g;
        int s = (i < dg) ? csr[row + i] : 0;
        float ev = as1[s * 8 + hl] + adv;
        ev = ev > 0.f ? ev : 0.2f * ev;
        float p = (i < dg) ? expf(ev - m) : 0.f;
        den += p;
        int nv = dg - base;
        if (nv > 8) nv = 8;
        for (int g2 = 0; g2 < nv; ++g2) {
            int sg = __shfl(s, g2 * 8);
            float xv0 = x1[(size_t)sg * NHID + lane];
            float xv1 = x1[(size_t)sg * NHID + 64 + lane];
#pragma unroll
            for (int h = 0; h < HEADS; ++h) {
                float ph = __shfl(p, g2 * 8 + h);
                acc[h][0] += xv0 * ph;
                acc[h][1] += xv1 * ph;
            }
        }
    }
    den += __shfl_xor(den, 8);
    den += __shfl_xor(den, 16);
    den += __shfl_xor(den, 32);
#pragma unroll
    for (int h = 0; h < HEADS; ++h) {
        float dh = __shfl(den, h);
        float inv = 1.f / (dh + 1e-16f);
        AGG[(size_t)d * 1024 + h * NHID + lane] = __float2bfloat16(acc[h][0] * inv);
        AGG[(size_t)d * 1024 + h * NHID + 64 + lane] = __float2bfloat16(acc[h][1] * inv);
    }
}

// Btil[(h*128+k)*64 + c] = W1[k, h*64+c] / 8
__global__ void btil_kernel(const float* __restrict__ W1, float* __restrict__ Btil) {
    int tid = blockIdx.x * 256 + threadIdx.x;
    if (tid >= 1024 * 64) return;
    int r = tid / 64, c = tid % 64;
    int h = r / NHID, k = r % NHID;
    Btil[tid] = W1[(size_t)k * (HEADS * NCLS) + h * NCLS + c] * 0.125f;
}

// out[n,c] = log_softmax(pre[n,c] + b1[c])
__global__ void logsoftmax_kernel(const float* __restrict__ pre, const float* __restrict__ b,
                                  float* __restrict__ out) {
    int gid = blockIdx.x * blockDim.x + threadIdx.x;
    int n = gid / 64;
    int c = threadIdx.x % 64;
    if (n >= NN) return;
    float z = pre[(size_t)n * 64 + c] + b[c];
    float mx = z;
#pragma unroll
    for (int off = 32; off > 0; off >>= 1) mx = fmaxf(mx, __shfl_xor(mx, off, 64));
    float s = expf(z - mx);
#pragma unroll
    for (int off = 32; off > 0; off >>= 1) s += __shfl_xor(s, off, 64);
    out[(size_t)n * 64 + c] = z - mx - logf(s);
}

// ---------------- launch ----------------

extern "C" void kernel_launch(void* const* d_in, const int* in_sizes, int n_in,
                              void* d_out, int out_size, void* d_ws, size_t ws_size,
                              hipStream_t stream) {
    const float* x   = (const float*)d_in[0];
    const int*   ei  = (const int*)d_in[1];
    const float* W0  = (const float*)d_in[2];
    const float* aS0 = (const float*)d_in[3];
    const float* aD0 = (const float*)d_in[4];
    const float* b0  = (const float*)d_in[5];
    const float* W1  = (const float*)d_in[6];
    const float* aS1 = (const float*)d_in[7];
    const float* aD1 = (const float*)d_in[8];
    const float* b1  = (const float*)d_in[9];
    float* out = (float*)d_out;

    char* ws = (char*)d_ws;
    float* x1   = (float*)ws; ws += (size_t)NN * NHID * 4;            // 25.6 MB
    float* h0   = (float*)ws; ws += (size_t)NN * NHID * 4;            // 25.6 MB
    __hip_bfloat16* AGG = (__hip_bfloat16*)ws; ws += (size_t)NN * 1024 * 2;  // 102.4 MB
    float* as0  = (float*)ws; ws += (size_t)NN * HEADS * 4;
    float* ad0  = (float*)ws; ws += (size_t)NN * HEADS * 4;
    float* as1  = (float*)ws; ws += (size_t)NN * HEADS * 4;
    float* ad1  = (float*)ws; ws += (size_t)NN * HEADS * 4;
    float* pre1 = (float*)ws; ws += (size_t)NN * NCLS * 4;            // 12.8 MB
    float* Btil = (float*)ws; ws += (size_t)1024 * 64 * 4;
    float* wS   = (float*)ws; ws += (size_t)HEADS * NHID * 4;
    float* wD   = (float*)ws; ws += (size_t)HEADS * NHID * 4;
    int* deg    = (int*)ws; ws += (size_t)NN * 4;
    int* rs     = (int*)ws; ws += (size_t)NN * 4;
    int* cnt2   = (int*)ws; ws += (size_t)NN * 4;
    int* bsum   = (int*)ws; ws += 256 * 4;
    int* bsumx  = (int*)ws; ws += 256 * 4;
    int* csr    = (int*)ws; ws += (size_t)NE * 4;                     // 2.4 MB

    const int NH = NN * HEADS;

    // ---- CSR build (shared by both layers) ----
    hipMemsetAsync(deg, 0, (size_t)NN * 4, stream);
    hipMemsetAsync(cnt2, 0, (size_t)NN * 4, stream);
    deg_kernel<<<(NE + 255) / 256, 256, 0, stream>>>(ei, deg);
    scan1_kernel<<<NB1, 256, 0, stream>>>(deg, rs, bsum);
    scan2_kernel<<<1, 256, 0, stream>>>(bsum, bsumx);
    scan3_kernel<<<NB1, 256, 0, stream>>>(rs, bsumx);
    scatter_kernel<<<(NE + 255) / 256, 256, 0, stream>>>(ei, rs, cnt2, csr);

    // ---- layer 0 ----
    gemm_f32<64, 64, 16, 4, 4><<<dim3((NN + 63) / 64, NHID / 64), 256, 0, stream>>>(
        x, W0, h0, NN, NHID, NF);
    alpha_kernel<<<(NH + 255) / 256, 256, 0, stream>>>(h0, aS0, aD0, as0, ad0, D0);
    fused_edge0<<<(NN + 3) / 4, 256, 0, stream>>>(rs, deg, csr, h0, as0, ad0, b0, x1);

    // ---- layer 1 (aggregate x1, GEMM after) ----
    wtil_kernel<<<4, 256, 0, stream>>>(W1, aS1, aD1, wS, wD);
    alpha1_kernel<<<(NH + 255) / 256, 256, 0, stream>>>(x1, wS, wD, as1, ad1);
    fused_edge1<<<(NN + 3) / 4, 256, 0, stream>>>(rs, deg, csr, x1, as1, ad1, AGG);
    btil_kernel<<<(1024 * 64 + 255) / 256, 256, 0, stream>>>(W1, Btil);
    gemm_bf16A<64, 64, 16, 4, 4><<<dim3((NN + 63) / 64, 1), 256, 0, stream>>>(
        AGG, Btil, pre1, NN, NCLS, 1024);

    // ---- output ----
    logsoftmax_kernel<<<(NN * 64 + 255) / 256, 256, 0, stream>>>(pre1, b1, out);
}

// Round 3
// 473.779 us; speedup vs baseline: 2.2752x; 1.3820x over previous
//
#include <hip/hip_runtime.h>
#include <hip/hip_bf16.h>
#include <math.h>

#define NN 50000
#define NE 600000
#define NF 256
#define NHID 128
#define HEADS 8
#define D0 16
#define NCLS 64
#define NB1 196  // (NN+255)/256

typedef __attribute__((ext_vector_type(8))) short short8;
typedef __attribute__((ext_vector_type(4))) float floatx4;

// ---------------- CSR build ----------------

__global__ void deg_kernel(const int* __restrict__ ei, int* __restrict__ deg) {
    int e = blockIdx.x * 256 + threadIdx.x;
    if (e < NE) atomicAdd(&deg[ei[NE + e]], 1);
}

__global__ void scan1_kernel(const int* __restrict__ deg, int* __restrict__ rs,
                             int* __restrict__ bsum) {
    __shared__ int sh[256];
    int tid = threadIdx.x;
    int i = blockIdx.x * 256 + tid;
    int v = (i < NN) ? deg[i] : 0;
    sh[tid] = v;
    __syncthreads();
    for (int off = 1; off < 256; off <<= 1) {
        int t = (tid >= off) ? sh[tid - off] : 0;
        __syncthreads();
        sh[tid] += t;
        __syncthreads();
    }
    if (i < NN) rs[i] = sh[tid] - v;  // exclusive
    if (tid == 255) bsum[blockIdx.x] = sh[255];
}

__global__ void scan2_kernel(const int* __restrict__ bsum, int* __restrict__ bsumx) {
    __shared__ int sh[256];
    int tid = threadIdx.x;
    int v = (tid < NB1) ? bsum[tid] : 0;
    sh[tid] = v;
    __syncthreads();
    for (int off = 1; off < 256; off <<= 1) {
        int t = (tid >= off) ? sh[tid - off] : 0;
        __syncthreads();
        sh[tid] += t;
        __syncthreads();
    }
    if (tid < NB1) bsumx[tid] = sh[tid] - v;
}

__global__ void scan3_kernel(int* __restrict__ rs, const int* __restrict__ bsumx) {
    int i = blockIdx.x * 256 + threadIdx.x;
    if (i < NN) rs[i] += bsumx[i >> 8];
}

__global__ void scatter_kernel(const int* __restrict__ ei, const int* __restrict__ rs,
                               int* __restrict__ cnt2, int* __restrict__ csr) {
    int e = blockIdx.x * 256 + threadIdx.x;
    if (e >= NE) return;
    int s = ei[e], d = ei[NE + e];
    int pos = rs[d] + atomicAdd(&cnt2[d], 1);
    csr[pos] = s;
}

// ---------------- casts & weight packing ----------------

__global__ void cast_bf16_kernel(const float* __restrict__ in, short* __restrict__ o, int n4) {
    int i = blockIdx.x * 256 + threadIdx.x;
    if (i >= n4) return;
    float4 v = ((const float4*)in)[i];
    short4 r;
    r.x = (short)__bfloat16_as_ushort(__float2bfloat16(v.x));
    r.y = (short)__bfloat16_as_ushort(__float2bfloat16(v.y));
    r.z = (short)__bfloat16_as_ushort(__float2bfloat16(v.z));
    r.w = (short)__bfloat16_as_ushort(__float2bfloat16(v.w));
    ((short4*)o)[i] = r;
}

// Bpack0[((t*8+ks)*64 + l)*8 + j] = bf16( W0[(ks*32 + (l>>4)*8 + j)*128 + t*16 + (l&15)] )
// t:0..7 colTile, ks:0..7
__global__ void pack_w0_kernel(const float* __restrict__ W0, short* __restrict__ Bp) {
    int tid = blockIdx.x * 256 + threadIdx.x;
    if (tid >= 8 * 8 * 64 * 8) return;
    int j = tid & 7, l = (tid >> 3) & 63, ks = (tid >> 9) & 7, t = tid >> 12;
    int k = ks * 32 + (l >> 4) * 8 + j;
    int c = t * 16 + (l & 15);
    Bp[tid] = (short)__bfloat16_as_ushort(__float2bfloat16(W0[(size_t)k * 128 + c]));
}

// Bpack1[((t*32+ks)*64 + l)*8 + j]: kk = ks*32 + (l>>4)*8 + j (0..1023), c = t*16+(l&15)
// value = W1[(kk&127)*512 + (kk>>7)*64 + c] * 0.125
__global__ void pack_w1_kernel(const float* __restrict__ W1, short* __restrict__ Bp) {
    int tid = blockIdx.x * 256 + threadIdx.x;
    if (tid >= 4 * 32 * 64 * 8) return;
    int j = tid & 7, l = (tid >> 3) & 63, ks = (tid >> 9) & 31, t = tid >> 14;
    int kk = ks * 32 + (l >> 4) * 8 + j;
    int c = t * 16 + (l & 15);
    float v = W1[(size_t)(kk & 127) * 512 + (kk >> 7) * 64 + c] * 0.125f;
    Bp[tid] = (short)__bfloat16_as_ushort(__float2bfloat16(v));
}

// ---------------- MFMA GEMMs ----------------

// h0[50000,128] = x_bf16[50000,256] @ W0  (block: 4 waves = 32 rows x 128 cols)
__global__ __launch_bounds__(256) void gemm0_mfma(const short* __restrict__ xb,
                                                  const short* __restrict__ Bp,
                                                  float* __restrict__ h0) {
    int lane = threadIdx.x & 63, wave = threadIdx.x >> 6;
    int rg = wave >> 1, cg = wave & 1;
    int q = lane >> 4, c16 = lane & 15;
    int row0 = blockIdx.x * 32 + rg * 16;
    int arow = row0 + c16;
    if (arow > NN - 1) arow = NN - 1;
    const short* ap = xb + (size_t)arow * NF + q * 8;
    floatx4 acc[4] = {};
#pragma unroll
    for (int ks = 0; ks < 8; ++ks) {
        short8 af = *(const short8*)(ap + ks * 32);
#pragma unroll
        for (int tt = 0; tt < 4; ++tt) {
            int t = cg * 4 + tt;
            short8 bf = *(const short8*)(Bp + (((size_t)t * 8 + ks) * 64 + lane) * 8);
            acc[tt] = __builtin_amdgcn_mfma_f32_16x16x32_bf16(af, bf, acc[tt], 0, 0, 0);
        }
    }
#pragma unroll
    for (int r = 0; r < 4; ++r) {
        int grow = row0 + q * 4 + r;
        if (grow >= NN) continue;
#pragma unroll
        for (int tt = 0; tt < 4; ++tt)
            h0[(size_t)grow * NHID + cg * 64 + tt * 16 + c16] = acc[tt][r];
    }
}

// out[50000,64] = log_softmax( AGG[50000,1024] @ Bpack1 + b1 )
// block: 4 waves = 64 rows; each wave 16 rows x 64 cols.
__global__ __launch_bounds__(256) void gemm1_mfma(const short* __restrict__ AGG,
                                                  const short* __restrict__ Bp,
                                                  const float* __restrict__ b1,
                                                  float* __restrict__ out) {
    int lane = threadIdx.x & 63, wave = threadIdx.x >> 6;
    int q = lane >> 4, c16 = lane & 15;
    int row0 = blockIdx.x * 64 + wave * 16;
    int arow = row0 + c16;
    if (arow > NN - 1) arow = NN - 1;
    const short* ap = AGG + (size_t)arow * 1024 + q * 8;
    floatx4 acc[4] = {};
    for (int ks = 0; ks < 32; ++ks) {
        short8 af = *(const short8*)(ap + ks * 32);
#pragma unroll
        for (int t = 0; t < 4; ++t) {
            short8 bf = *(const short8*)(Bp + (((size_t)t * 32 + ks) * 64 + lane) * 8);
            acc[t] = __builtin_amdgcn_mfma_f32_16x16x32_bf16(af, bf, acc[t], 0, 0, 0);
        }
    }
    // epilogue: bias + log_softmax per row; row = row0 + q*4 + r, cols t*16+c16
    float bias[4];
#pragma unroll
    for (int t = 0; t < 4; ++t) bias[t] = b1[t * 16 + c16];
#pragma unroll
    for (int r = 0; r < 4; ++r) {
        int grow = row0 + q * 4 + r;
        float z[4];
        float mx = -INFINITY;
#pragma unroll
        for (int t = 0; t < 4; ++t) {
            z[t] = acc[t][r] + bias[t];
            mx = fmaxf(mx, z[t]);
        }
        mx = fmaxf(mx, __shfl_xor(mx, 1));
        mx = fmaxf(mx, __shfl_xor(mx, 2));
        mx = fmaxf(mx, __shfl_xor(mx, 4));
        mx = fmaxf(mx, __shfl_xor(mx, 8));
        float s = 0.f;
#pragma unroll
        for (int t = 0; t < 4; ++t) s += expf(z[t] - mx);
        s += __shfl_xor(s, 1);
        s += __shfl_xor(s, 2);
        s += __shfl_xor(s, 4);
        s += __shfl_xor(s, 8);
        float lse = mx + logf(s);
        if (grow < NN) {
#pragma unroll
            for (int t = 0; t < 4; ++t)
                out[(size_t)grow * NCLS + t * 16 + c16] = z[t] - lse;
        }
    }
}

// ---------------- attention logits ----------------
__global__ void alpha_kernel(const float* __restrict__ h, const float* __restrict__ a_s,
                             const float* __restrict__ a_d, float* __restrict__ as_out,
                             float* __restrict__ ad_out, int D) {
    int idx = blockIdx.x * blockDim.x + threadIdx.x;
    if (idx >= NN * HEADS) return;
    int n = idx / HEADS, hh = idx % HEADS;
    const float* hp = h + (size_t)n * HEADS * D + hh * D;
    const float* asp = a_s + hh * D;
    const float* adp = a_d + hh * D;
    float s = 0.f, d = 0.f;
    for (int i = 0; i < D; ++i) {
        float v = hp[i];
        s += v * asp[i];
        d += v * adp[i];
    }
    as_out[idx] = s;
    ad_out[idx] = d;
}

// w~[h,k] = sum_d W1[k, h*64+d] * a[h,d]
__global__ void wtil_kernel(const float* __restrict__ W1, const float* __restrict__ aS,
                            const float* __restrict__ aD, float* __restrict__ wS,
                            float* __restrict__ wD) {
    int tid = blockIdx.x * 256 + threadIdx.x;
    if (tid >= HEADS * NHID) return;
    int h = tid / NHID, k = tid % NHID;
    float sS = 0.f, sD = 0.f;
    for (int d2 = 0; d2 < NCLS; ++d2) {
        float w = W1[(size_t)k * (HEADS * NCLS) + h * NCLS + d2];
        sS += w * aS[h * NCLS + d2];
        sD += w * aD[h * NCLS + d2];
    }
    wS[tid] = sS;
    wD[tid] = sD;
}

// as1[n,h] = x1[n,:] . wS[h,:]
__global__ void alpha1_kernel(const float* __restrict__ x1, const float* __restrict__ wS,
                              const float* __restrict__ wD, float* __restrict__ as_out,
                              float* __restrict__ ad_out) {
    int idx = blockIdx.x * 256 + threadIdx.x;
    if (idx >= NN * HEADS) return;
    int n = idx / HEADS, h = idx % HEADS;
    const float* xp = x1 + (size_t)n * NHID;
    const float* sp = wS + h * NHID;
    const float* dp = wD + h * NHID;
    float s = 0.f, d = 0.f;
    for (int k = 0; k < NHID; ++k) {
        float v = xp[k];
        s += v * sp[k];
        d += v * dp[k];
    }
    as_out[idx] = s;
    ad_out[idx] = d;
}

// ---------------- fused edge kernels (one wave per dst node) ----------------

__global__ __launch_bounds__(256) void fused_edge0(
    const int* __restrict__ rs, const int* __restrict__ deg, const int* __restrict__ csr,
    const float* __restrict__ h0, const float* __restrict__ as0, const float* __restrict__ ad0,
    const float* __restrict__ b0, float* __restrict__ x1) {
    int d = (blockIdx.x * 256 + threadIdx.x) >> 6;
    int lane = threadIdx.x & 63;
    if (d >= NN) return;
    int row = rs[d], dg = deg[d];
    int hl = lane & 7, g = lane >> 3;
    float adv = ad0[d * 8 + hl];
    float m = -INFINITY;
    for (int base = 0; base < dg; base += 8) {
        int i = base + g;
        int s = (i < dg) ? csr[row + i] : 0;
        float ev = as0[s * 8 + hl] + adv;
        ev = ev > 0.f ? ev : 0.2f * ev;
        if (i < dg) m = fmaxf(m, ev);
    }
    m = fmaxf(m, __shfl_xor(m, 8));
    m = fmaxf(m, __shfl_xor(m, 16));
    m = fmaxf(m, __shfl_xor(m, 32));
    float den = 0.f, acc0 = 0.f, acc1 = 0.f;
    int hd0 = lane >> 4;
    for (int base = 0; base < dg; base += 8) {
        int i = base + g;
        int s = (i < dg) ? csr[row + i] : 0;
        float ev = as0[s * 8 + hl] + adv;
        ev = ev > 0.f ? ev : 0.2f * ev;
        float p = (i < dg) ? expf(ev - m) : 0.f;
        den += p;
        int nv = dg - base;
        if (nv > 8) nv = 8;
        for (int g2 = 0; g2 < nv; ++g2) {
            int sg = __shfl(s, g2 * 8);
            float p0 = __shfl(p, g2 * 8 + hd0);
            float p1 = __shfl(p, g2 * 8 + hd0 + 4);
            acc0 += h0[(size_t)sg * NHID + lane] * p0;
            acc1 += h0[(size_t)sg * NHID + 64 + lane] * p1;
        }
    }
    den += __shfl_xor(den, 8);
    den += __shfl_xor(den, 16);
    den += __shfl_xor(den, 32);
    float d0 = __shfl(den, hd0);
    float d1 = __shfl(den, hd0 + 4);
    float o0 = acc0 / (d0 + 1e-16f) + b0[lane];
    float o1 = acc1 / (d1 + 1e-16f) + b0[64 + lane];
    o0 = o0 > 0.f ? o0 : expf(o0) - 1.f;
    o1 = o1 > 0.f ? o1 : expf(o1) - 1.f;
    x1[(size_t)d * NHID + lane] = o0;
    x1[(size_t)d * NHID + 64 + lane] = o1;
}

__global__ __launch_bounds__(256) void fused_edge1(
    const int* __restrict__ rs, const int* __restrict__ deg, const int* __restrict__ csr,
    const float* __restrict__ x1, const float* __restrict__ as1, const float* __restrict__ ad1,
    __hip_bfloat16* __restrict__ AGG) {
    int d = (blockIdx.x * 256 + threadIdx.x) >> 6;
    int lane = threadIdx.x & 63;
    if (d >= NN) return;
    int row = rs[d], dg = deg[d];
    int hl = lane & 7, g = lane >> 3;
    float adv = ad1[d * 8 + hl];
    float m = -INFINITY;
    for (int base = 0; base < dg; base += 8) {
        int i = base + g;
        int s = (i < dg) ? csr[row + i] : 0;
        float ev = as1[s * 8 + hl] + adv;
        ev = ev > 0.f ? ev : 0.2f * ev;
        if (i < dg) m = fmaxf(m, ev);
    }
    m = fmaxf(m, __shfl_xor(m, 8));
    m = fmaxf(m, __shfl_xor(m, 16));
    m = fmaxf(m, __shfl_xor(m, 32));
    float den = 0.f;
    float acc[HEADS][2] = {};
    for (int base = 0; base < dg; base += 8) {
        int i = base + g;
        int s = (i < dg) ? csr[row + i] : 0;
        float ev = as1[s * 8 + hl] + adv;
        ev = ev > 0.f ? ev : 0.2f * ev;
        float p = (i < dg) ? expf(ev - m) : 0.f;
        den += p;
        int nv = dg - base;
        if (nv > 8) nv = 8;
        for (int g2 = 0; g2 < nv; ++g2) {
            int sg = __shfl(s, g2 * 8);
            float xv0 = x1[(size_t)sg * NHID + lane];
            float xv1 = x1[(size_t)sg * NHID + 64 + lane];
#pragma unroll
            for (int h = 0; h < HEADS; ++h) {
                float ph = __shfl(p, g2 * 8 + h);
                acc[h][0] += xv0 * ph;
                acc[h][1] += xv1 * ph;
            }
        }
    }
    den += __shfl_xor(den, 8);
    den += __shfl_xor(den, 16);
    den += __shfl_xor(den, 32);
#pragma unroll
    for (int h = 0; h < HEADS; ++h) {
        float dh = __shfl(den, h);
        float inv = 1.f / (dh + 1e-16f);
        AGG[(size_t)d * 1024 + h * NHID + lane] = __float2bfloat16(acc[h][0] * inv);
        AGG[(size_t)d * 1024 + h * NHID + 64 + lane] = __float2bfloat16(acc[h][1] * inv);
    }
}

// ---------------- launch ----------------

extern "C" void kernel_launch(void* const* d_in, const int* in_sizes, int n_in,
                              void* d_out, int out_size, void* d_ws, size_t ws_size,
                              hipStream_t stream) {
    const float* x   = (const float*)d_in[0];
    const int*   ei  = (const int*)d_in[1];
    const float* W0  = (const float*)d_in[2];
    const float* aS0 = (const float*)d_in[3];
    const float* aD0 = (const float*)d_in[4];
    const float* b0  = (const float*)d_in[5];
    const float* W1  = (const float*)d_in[6];
    const float* aS1 = (const float*)d_in[7];
    const float* aD1 = (const float*)d_in[8];
    const float* b1  = (const float*)d_in[9];
    float* out = (float*)d_out;

    char* ws = (char*)d_ws;
    float* x1   = (float*)ws; ws += (size_t)NN * NHID * 4;            // 25.6 MB
    float* h0   = (float*)ws; ws += (size_t)NN * NHID * 4;            // 25.6 MB
    __hip_bfloat16* AGG = (__hip_bfloat16*)ws; ws += (size_t)NN * 1024 * 2;  // 102.4 MB
    short* xb   = (short*)ws; ws += (size_t)NN * NF * 2;              // 25.6 MB
    float* as0  = (float*)ws; ws += (size_t)NN * HEADS * 4;
    float* ad0  = (float*)ws; ws += (size_t)NN * HEADS * 4;
    float* as1  = (float*)ws; ws += (size_t)NN * HEADS * 4;
    float* ad1  = (float*)ws; ws += (size_t)NN * HEADS * 4;
    short* Bp0  = (short*)ws; ws += (size_t)8 * 8 * 64 * 8 * 2;       // 64 KB
    short* Bp1  = (short*)ws; ws += (size_t)4 * 32 * 64 * 8 * 2;      // 128 KB
    float* wS   = (float*)ws; ws += (size_t)HEADS * NHID * 4;
    float* wD   = (float*)ws; ws += (size_t)HEADS * NHID * 4;
    int* deg    = (int*)ws; ws += (size_t)NN * 4;
    int* rs     = (int*)ws; ws += (size_t)NN * 4;
    int* cnt2   = (int*)ws; ws += (size_t)NN * 4;
    int* bsum   = (int*)ws; ws += 256 * 4;
    int* bsumx  = (int*)ws; ws += 256 * 4;
    int* csr    = (int*)ws; ws += (size_t)NE * 4;                     // 2.4 MB

    const int NH = NN * HEADS;

    // ---- CSR build (shared by both layers) ----
    hipMemsetAsync(deg, 0, (size_t)NN * 4, stream);
    hipMemsetAsync(cnt2, 0, (size_t)NN * 4, stream);
    deg_kernel<<<(NE + 255) / 256, 256, 0, stream>>>(ei, deg);
    scan1_kernel<<<NB1, 256, 0, stream>>>(deg, rs, bsum);
    scan2_kernel<<<1, 256, 0, stream>>>(bsum, bsumx);
    scan3_kernel<<<NB1, 256, 0, stream>>>(rs, bsumx);
    scatter_kernel<<<(NE + 255) / 256, 256, 0, stream>>>(ei, rs, cnt2, csr);

    // ---- layer 0 ----
    cast_bf16_kernel<<<(NN * NF / 4 + 255) / 256, 256, 0, stream>>>(x, xb, NN * NF / 4);
    pack_w0_kernel<<<(8 * 8 * 64 * 8 + 255) / 256, 256, 0, stream>>>(W0, Bp0);
    gemm0_mfma<<<(NN + 31) / 32, 256, 0, stream>>>(xb, Bp0, h0);
    alpha_kernel<<<(NH + 255) / 256, 256, 0, stream>>>(h0, aS0, aD0, as0, ad0, D0);
    fused_edge0<<<(NN + 3) / 4, 256, 0, stream>>>(rs, deg, csr, h0, as0, ad0, b0, x1);

    // ---- layer 1 (aggregate x1, GEMM after) ----
    wtil_kernel<<<4, 256, 0, stream>>>(W1, aS1, aD1, wS, wD);
    alpha1_kernel<<<(NH + 255) / 256, 256, 0, stream>>>(x1, wS, wD, as1, ad1);
    fused_edge1<<<(NN + 3) / 4, 256, 0, stream>>>(rs, deg, csr, x1, as1, ad1, AGG);
    pack_w1_kernel<<<(4 * 32 * 64 * 8 + 255) / 256, 256, 0, stream>>>(W1, Bp1);
    gemm1_mfma<<<(NN + 63) / 64, 256, 0, stream>>>((const short*)AGG, Bp1, b1, out);
}

// Round 4
// 424.693 us; speedup vs baseline: 2.5382x; 1.1156x over previous
//
#include <hip/hip_runtime.h>
#include <hip/hip_bf16.h>
#include <math.h>

#define NN 50000
#define NE 600000
#define NF 256
#define NHID 128
#define HEADS 8
#define D0 16
#define NCLS 64
#define NB1 196  // (NN+255)/256

typedef __attribute__((ext_vector_type(8))) short short8;
typedef __attribute__((ext_vector_type(4))) float floatx4;

__device__ __forceinline__ float bf16lo(uint v) { return __uint_as_float((v & 0xffffu) << 16); }
__device__ __forceinline__ float bf16hi(uint v) { return __uint_as_float(v & 0xffff0000u); }
__device__ __forceinline__ uint packbf16(float a, float b) {
    return (uint)__bfloat16_as_ushort(__float2bfloat16(a)) |
           ((uint)__bfloat16_as_ushort(__float2bfloat16(b)) << 16);
}

// ---------------- CSR build ----------------

__global__ void deg_kernel(const int* __restrict__ ei, int* __restrict__ deg) {
    int e = blockIdx.x * 256 + threadIdx.x;
    if (e < NE) atomicAdd(&deg[ei[NE + e]], 1);
}

__global__ void scan1_kernel(const int* __restrict__ deg, int* __restrict__ rs,
                             int* __restrict__ bsum) {
    __shared__ int sh[256];
    int tid = threadIdx.x;
    int i = blockIdx.x * 256 + tid;
    int v = (i < NN) ? deg[i] : 0;
    sh[tid] = v;
    __syncthreads();
    for (int off = 1; off < 256; off <<= 1) {
        int t = (tid >= off) ? sh[tid - off] : 0;
        __syncthreads();
        sh[tid] += t;
        __syncthreads();
    }
    if (i < NN) rs[i] = sh[tid] - v;  // exclusive
    if (tid == 255) bsum[blockIdx.x] = sh[255];
}

__global__ void scan2_kernel(const int* __restrict__ bsum, int* __restrict__ bsumx) {
    __shared__ int sh[256];
    int tid = threadIdx.x;
    int v = (tid < NB1) ? bsum[tid] : 0;
    sh[tid] = v;
    __syncthreads();
    for (int off = 1; off < 256; off <<= 1) {
        int t = (tid >= off) ? sh[tid - off] : 0;
        __syncthreads();
        sh[tid] += t;
        __syncthreads();
    }
    if (tid < NB1) bsumx[tid] = sh[tid] - v;
}

__global__ void scan3_kernel(int* __restrict__ rs, const int* __restrict__ bsumx) {
    int i = blockIdx.x * 256 + threadIdx.x;
    if (i < NN) rs[i] += bsumx[i >> 8];
}

__global__ void scatter_kernel(const int* __restrict__ ei, const int* __restrict__ rs,
                               int* __restrict__ cnt2, int* __restrict__ csr) {
    int e = blockIdx.x * 256 + threadIdx.x;
    if (e >= NE) return;
    int s = ei[e], d = ei[NE + e];
    int pos = rs[d] + atomicAdd(&cnt2[d], 1);
    csr[pos] = s;
}

// ---------------- casts & weight packing ----------------

__global__ void cast_bf16_kernel(const float* __restrict__ in, short* __restrict__ o, int n4) {
    int i = blockIdx.x * 256 + threadIdx.x;
    if (i >= n4) return;
    float4 v = ((const float4*)in)[i];
    short4 r;
    r.x = (short)__bfloat16_as_ushort(__float2bfloat16(v.x));
    r.y = (short)__bfloat16_as_ushort(__float2bfloat16(v.y));
    r.z = (short)__bfloat16_as_ushort(__float2bfloat16(v.z));
    r.w = (short)__bfloat16_as_ushort(__float2bfloat16(v.w));
    ((short4*)o)[i] = r;
}

// Bpack0[((t*8+ks)*64 + l)*8 + j] = bf16( W0[(ks*32 + (l>>4)*8 + j)*128 + t*16 + (l&15)] )
__global__ void pack_w0_kernel(const float* __restrict__ W0, short* __restrict__ Bp) {
    int tid = blockIdx.x * 256 + threadIdx.x;
    if (tid >= 8 * 8 * 64 * 8) return;
    int j = tid & 7, l = (tid >> 3) & 63, ks = (tid >> 9) & 7, t = tid >> 12;
    int k = ks * 32 + (l >> 4) * 8 + j;
    int c = t * 16 + (l & 15);
    Bp[tid] = (short)__bfloat16_as_ushort(__float2bfloat16(W0[(size_t)k * 128 + c]));
}

// Bpack1[((t*32+ks)*64 + l)*8 + j]: kk = ks*32 + (l>>4)*8 + j, c = t*16+(l&15)
__global__ void pack_w1_kernel(const float* __restrict__ W1, short* __restrict__ Bp) {
    int tid = blockIdx.x * 256 + threadIdx.x;
    if (tid >= 4 * 32 * 64 * 8) return;
    int j = tid & 7, l = (tid >> 3) & 63, ks = (tid >> 9) & 31, t = tid >> 14;
    int kk = ks * 32 + (l >> 4) * 8 + j;
    int c = t * 16 + (l & 15);
    float v = W1[(size_t)(kk & 127) * 512 + (kk >> 7) * 64 + c] * 0.125f;
    Bp[tid] = (short)__bfloat16_as_ushort(__float2bfloat16(v));
}

// ---------------- MFMA GEMMs ----------------

// h0b[50000,128](bf16) = x_bf16[50000,256] @ W0
__global__ __launch_bounds__(256) void gemm0_mfma(const short* __restrict__ xb,
                                                  const short* __restrict__ Bp,
                                                  ushort* __restrict__ h0b) {
    int lane = threadIdx.x & 63, wave = threadIdx.x >> 6;
    int rg = wave >> 1, cg = wave & 1;
    int q = lane >> 4, c16 = lane & 15;
    int row0 = blockIdx.x * 32 + rg * 16;
    int arow = row0 + c16;
    if (arow > NN - 1) arow = NN - 1;
    const short* ap = xb + (size_t)arow * NF + q * 8;
    floatx4 acc[4] = {};
#pragma unroll
    for (int ks = 0; ks < 8; ++ks) {
        short8 af = *(const short8*)(ap + ks * 32);
#pragma unroll
        for (int tt = 0; tt < 4; ++tt) {
            int t = cg * 4 + tt;
            short8 bf = *(const short8*)(Bp + (((size_t)t * 8 + ks) * 64 + lane) * 8);
            acc[tt] = __builtin_amdgcn_mfma_f32_16x16x32_bf16(af, bf, acc[tt], 0, 0, 0);
        }
    }
#pragma unroll
    for (int r = 0; r < 4; ++r) {
        int grow = row0 + q * 4 + r;
        if (grow >= NN) continue;
#pragma unroll
        for (int tt = 0; tt < 4; ++tt)
            h0b[(size_t)grow * NHID + cg * 64 + tt * 16 + c16] =
                __bfloat16_as_ushort(__float2bfloat16(acc[tt][r]));
    }
}

// out[50000,64] = log_softmax( AGG[50000,1024] @ Bpack1 + b1 )
__global__ __launch_bounds__(256) void gemm1_mfma(const short* __restrict__ AGG,
                                                  const short* __restrict__ Bp,
                                                  const float* __restrict__ b1,
                                                  float* __restrict__ out) {
    int lane = threadIdx.x & 63, wave = threadIdx.x >> 6;
    int q = lane >> 4, c16 = lane & 15;
    int row0 = blockIdx.x * 64 + wave * 16;
    int arow = row0 + c16;
    if (arow > NN - 1) arow = NN - 1;
    const short* ap = AGG + (size_t)arow * 1024 + q * 8;
    floatx4 acc[4] = {};
    for (int ks = 0; ks < 32; ++ks) {
        short8 af = *(const short8*)(ap + ks * 32);
#pragma unroll
        for (int t = 0; t < 4; ++t) {
            short8 bf = *(const short8*)(Bp + (((size_t)t * 32 + ks) * 64 + lane) * 8);
            acc[t] = __builtin_amdgcn_mfma_f32_16x16x32_bf16(af, bf, acc[t], 0, 0, 0);
        }
    }
    float bias[4];
#pragma unroll
    for (int t = 0; t < 4; ++t) bias[t] = b1[t * 16 + c16];
#pragma unroll
    for (int r = 0; r < 4; ++r) {
        int grow = row0 + q * 4 + r;
        float z[4];
        float mx = -INFINITY;
#pragma unroll
        for (int t = 0; t < 4; ++t) {
            z[t] = acc[t][r] + bias[t];
            mx = fmaxf(mx, z[t]);
        }
        mx = fmaxf(mx, __shfl_xor(mx, 1));
        mx = fmaxf(mx, __shfl_xor(mx, 2));
        mx = fmaxf(mx, __shfl_xor(mx, 4));
        mx = fmaxf(mx, __shfl_xor(mx, 8));
        float s = 0.f;
#pragma unroll
        for (int t = 0; t < 4; ++t) s += expf(z[t] - mx);
        s += __shfl_xor(s, 1);
        s += __shfl_xor(s, 2);
        s += __shfl_xor(s, 4);
        s += __shfl_xor(s, 8);
        float lse = mx + logf(s);
        if (grow < NN) {
#pragma unroll
            for (int t = 0; t < 4; ++t)
                out[(size_t)grow * NCLS + t * 16 + c16] = z[t] - lse;
        }
    }
}

// ---------------- attention logits ----------------
__global__ void alpha_kernel(const ushort* __restrict__ h, const float* __restrict__ a_s,
                             const float* __restrict__ a_d, float* __restrict__ as_out,
                             float* __restrict__ ad_out) {
    int idx = blockIdx.x * blockDim.x + threadIdx.x;
    if (idx >= NN * HEADS) return;
    int n = idx / HEADS, hh = idx % HEADS;
    const ushort* hp = h + (size_t)n * NHID + hh * D0;
    const float* asp = a_s + hh * D0;
    const float* adp = a_d + hh * D0;
    float s = 0.f, d = 0.f;
    for (int i = 0; i < D0; ++i) {
        float v = __uint_as_float(((uint)hp[i]) << 16);
        s += v * asp[i];
        d += v * adp[i];
    }
    as_out[idx] = s;
    ad_out[idx] = d;
}

// w~[h,k] = sum_d W1[k, h*64+d] * a[h,d]
__global__ void wtil_kernel(const float* __restrict__ W1, const float* __restrict__ aS,
                            const float* __restrict__ aD, float* __restrict__ wS,
                            float* __restrict__ wD) {
    int tid = blockIdx.x * 256 + threadIdx.x;
    if (tid >= HEADS * NHID) return;
    int h = tid / NHID, k = tid % NHID;
    float sS = 0.f, sD = 0.f;
    for (int d2 = 0; d2 < NCLS; ++d2) {
        float w = W1[(size_t)k * (HEADS * NCLS) + h * NCLS + d2];
        sS += w * aS[h * NCLS + d2];
        sD += w * aD[h * NCLS + d2];
    }
    wS[tid] = sS;
    wD[tid] = sD;
}

// as1[n,h] = x1[n,:] . wS[h,:]   (x1 in bf16)
__global__ void alpha1_kernel(const ushort* __restrict__ x1b, const float* __restrict__ wS,
                              const float* __restrict__ wD, float* __restrict__ as_out,
                              float* __restrict__ ad_out) {
    int idx = blockIdx.x * 256 + threadIdx.x;
    if (idx >= NN * HEADS) return;
    int n = idx / HEADS, h = idx % HEADS;
    const ushort* xp = x1b + (size_t)n * NHID;
    const float* sp = wS + h * NHID;
    const float* dp = wD + h * NHID;
    float s = 0.f, d = 0.f;
    for (int k = 0; k < NHID; ++k) {
        float v = __uint_as_float(((uint)xp[k]) << 16);
        s += v * sp[k];
        d += v * dp[k];
    }
    as_out[idx] = s;
    ad_out[idx] = d;
}

// ---------------- fused edge kernels (one wave per dst node, single pass) ----------------
// softmax computed WITHOUT max subtraction (shift-invariant; logits are O(+-6) here)

__global__ __launch_bounds__(256) void fused_edge0(
    const int* __restrict__ rs, const int* __restrict__ deg, const int* __restrict__ csr,
    const ushort* __restrict__ h0b, const float* __restrict__ as0, const float* __restrict__ ad0,
    const float* __restrict__ b0, ushort* __restrict__ x1b) {
    int d = (blockIdx.x * 256 + threadIdx.x) >> 6;
    int lane = threadIdx.x & 63;
    if (d >= NN) return;
    int row = rs[d], dg = deg[d];
    int hl = lane & 7, g = lane >> 3;
    int hp = lane >> 3;  // head owning this lane's dim pair (2*lane, 2*lane+1)
    float adv = ad0[d * 8 + hl];
    float den = 0.f, acc0 = 0.f, acc1 = 0.f;
    for (int base = 0; base < dg; base += 8) {
        int i = base + g;
        int s = (i < dg) ? csr[row + i] : 0;
        float ev = as0[s * 8 + hl] + adv;
        ev = ev > 0.f ? ev : 0.2f * ev;
        float p = (i < dg) ? __expf(ev) : 0.f;
        den += p;
        int nv = dg - base;
        if (nv > 8) nv = 8;
        for (int g2 = 0; g2 < nv; ++g2) {
            int sg = __shfl(s, g2 * 8);
            float ph = __shfl(p, g2 * 8 + hp);
            uint v = *(const uint*)(h0b + (size_t)sg * NHID + 2 * lane);
            acc0 += bf16lo(v) * ph;
            acc1 += bf16hi(v) * ph;
        }
    }
    den += __shfl_xor(den, 8);
    den += __shfl_xor(den, 16);
    den += __shfl_xor(den, 32);
    float dh = __shfl(den, hp);
    float inv = 1.f / (dh + 1e-16f);
    float2 bb = ((const float2*)b0)[lane];
    float o0 = acc0 * inv + bb.x;
    float o1 = acc1 * inv + bb.y;
    o0 = o0 > 0.f ? o0 : expf(o0) - 1.f;
    o1 = o1 > 0.f ? o1 : expf(o1) - 1.f;
    *(uint*)(x1b + (size_t)d * NHID + 2 * lane) = packbf16(o0, o1);
}

__global__ __launch_bounds__(256) void fused_edge1(
    const int* __restrict__ rs, const int* __restrict__ deg, const int* __restrict__ csr,
    const ushort* __restrict__ x1b, const float* __restrict__ as1, const float* __restrict__ ad1,
    ushort* __restrict__ AGG) {
    int d = (blockIdx.x * 256 + threadIdx.x) >> 6;
    int lane = threadIdx.x & 63;
    if (d >= NN) return;
    int row = rs[d], dg = deg[d];
    int hl = lane & 7, g = lane >> 3;
    float adv = ad1[d * 8 + hl];
    float den = 0.f;
    float acc[HEADS][2] = {};
    for (int base = 0; base < dg; base += 8) {
        int i = base + g;
        int s = (i < dg) ? csr[row + i] : 0;
        float ev = as1[s * 8 + hl] + adv;
        ev = ev > 0.f ? ev : 0.2f * ev;
        float p = (i < dg) ? __expf(ev) : 0.f;
        den += p;
        int nv = dg - base;
        if (nv > 8) nv = 8;
        for (int g2 = 0; g2 < nv; ++g2) {
            int sg = __shfl(s, g2 * 8);
            uint v = *(const uint*)(x1b + (size_t)sg * NHID + 2 * lane);
            float lo = bf16lo(v), hi = bf16hi(v);
#pragma unroll
            for (int h = 0; h < HEADS; ++h) {
                float ph = __shfl(p, g2 * 8 + h);
                acc[h][0] += lo * ph;
                acc[h][1] += hi * ph;
            }
        }
    }
    den += __shfl_xor(den, 8);
    den += __shfl_xor(den, 16);
    den += __shfl_xor(den, 32);
#pragma unroll
    for (int h = 0; h < HEADS; ++h) {
        float dh = __shfl(den, h);
        float inv = 1.f / (dh + 1e-16f);
        *(uint*)(AGG + (size_t)d * 1024 + h * NHID + 2 * lane) =
            packbf16(acc[h][0] * inv, acc[h][1] * inv);
    }
}

// ---------------- launch ----------------

extern "C" void kernel_launch(void* const* d_in, const int* in_sizes, int n_in,
                              void* d_out, int out_size, void* d_ws, size_t ws_size,
                              hipStream_t stream) {
    const float* x   = (const float*)d_in[0];
    const int*   ei  = (const int*)d_in[1];
    const float* W0  = (const float*)d_in[2];
    const float* aS0 = (const float*)d_in[3];
    const float* aD0 = (const float*)d_in[4];
    const float* b0  = (const float*)d_in[5];
    const float* W1  = (const float*)d_in[6];
    const float* aS1 = (const float*)d_in[7];
    const float* aD1 = (const float*)d_in[8];
    const float* b1  = (const float*)d_in[9];
    float* out = (float*)d_out;

    char* ws = (char*)d_ws;
    ushort* x1b = (ushort*)ws; ws += (size_t)NN * NHID * 2;           // 12.8 MB
    ushort* h0b = (ushort*)ws; ws += (size_t)NN * NHID * 2;           // 12.8 MB
    ushort* AGG = (ushort*)ws; ws += (size_t)NN * 1024 * 2;           // 102.4 MB
    short* xb   = (short*)ws; ws += (size_t)NN * NF * 2;              // 25.6 MB
    float* as0  = (float*)ws; ws += (size_t)NN * HEADS * 4;
    float* ad0  = (float*)ws; ws += (size_t)NN * HEADS * 4;
    float* as1  = (float*)ws; ws += (size_t)NN * HEADS * 4;
    float* ad1  = (float*)ws; ws += (size_t)NN * HEADS * 4;
    short* Bp0  = (short*)ws; ws += (size_t)8 * 8 * 64 * 8 * 2;       // 64 KB
    short* Bp1  = (short*)ws; ws += (size_t)4 * 32 * 64 * 8 * 2;      // 128 KB
    float* wS   = (float*)ws; ws += (size_t)HEADS * NHID * 4;
    float* wD   = (float*)ws; ws += (size_t)HEADS * NHID * 4;
    int* deg    = (int*)ws; ws += (size_t)NN * 4;
    int* rs     = (int*)ws; ws += (size_t)NN * 4;
    int* cnt2   = (int*)ws; ws += (size_t)NN * 4;
    int* bsum   = (int*)ws; ws += 256 * 4;
    int* bsumx  = (int*)ws; ws += 256 * 4;
    int* csr    = (int*)ws; ws += (size_t)NE * 4;                     // 2.4 MB

    const int NH = NN * HEADS;

    // ---- CSR build (shared by both layers) ----
    hipMemsetAsync(deg, 0, (size_t)NN * 4, stream);
    hipMemsetAsync(cnt2, 0, (size_t)NN * 4, stream);
    deg_kernel<<<(NE + 255) / 256, 256, 0, stream>>>(ei, deg);
    scan1_kernel<<<NB1, 256, 0, stream>>>(deg, rs, bsum);
    scan2_kernel<<<1, 256, 0, stream>>>(bsum, bsumx);
    scan3_kernel<<<NB1, 256, 0, stream>>>(rs, bsumx);
    scatter_kernel<<<(NE + 255) / 256, 256, 0, stream>>>(ei, rs, cnt2, csr);

    // ---- layer 0 ----
    cast_bf16_kernel<<<(NN * NF / 4 + 255) / 256, 256, 0, stream>>>(x, xb, NN * NF / 4);
    pack_w0_kernel<<<(8 * 8 * 64 * 8 + 255) / 256, 256, 0, stream>>>(W0, Bp0);
    gemm0_mfma<<<(NN + 31) / 32, 256, 0, stream>>>(xb, Bp0, h0b);
    alpha_kernel<<<(NH + 255) / 256, 256, 0, stream>>>(h0b, aS0, aD0, as0, ad0);
    fused_edge0<<<(NN + 3) / 4, 256, 0, stream>>>(rs, deg, csr, h0b, as0, ad0, b0, x1b);

    // ---- layer 1 (aggregate x1, GEMM after) ----
    wtil_kernel<<<4, 256, 0, stream>>>(W1, aS1, aD1, wS, wD);
    alpha1_kernel<<<(NH + 255) / 256, 256, 0, stream>>>(x1b, wS, wD, as1, ad1);
    fused_edge1<<<(NN + 3) / 4, 256, 0, stream>>>(rs, deg, csr, x1b, as1, ad1, AGG);
    pack_w1_kernel<<<(4 * 32 * 64 * 8 + 255) / 256, 256, 0, stream>>>(W1, Bp1);
    gemm1_mfma<<<(NN + 63) / 64, 256, 0, stream>>>((const short*)AGG, Bp1, b1, out);
}